// Round 6
// baseline (412.914 us; speedup 1.0000x reference)
//
#include <hip/hip_runtime.h>

#define N_NODES 59392
#define N_EDGES 1187840
#define F_IN 116
#define F_HID 64
#define BATCH 512
#define NPG 116            // nodes per graph
#define NS 64              // edge slices
#define NR 4               // node ranges
#define EPSL (N_EDGES / NS)   // 18560 edges per slice (exact)
#define NPR (N_NODES / NR)    // 14848 nodes per range (exact)
#define CCAP 64            // bucket: 64 u16 = one 128B line per node; P(indeg>64)~1e-15, guarded

// ---------------------------------------------------------------- kernel A: LDS histograms + gemm1
// Blocks [0,256): (slice,range) pairs — histogram dst then src of their slice into
// 14848 LDS u32 bins (LDS atomics: no memory-side atomic stream), write u16 partials
// as clean coalesced lines. All 512 blocks then run gemm1 (A1 = feat @ W1; onorm
// deferred into the gather by linearity).
__global__ __launch_bounds__(256) void hist_gemm1_kernel(const int* __restrict__ src,
                                                         const int* __restrict__ dst,
                                                         unsigned short* __restrict__ cnt2,
                                                         unsigned short* __restrict__ cnt2s,
                                                         const float* __restrict__ feat,
                                                         const float* __restrict__ W1,
                                                         float* __restrict__ A1) {
    __shared__ union U {
        unsigned bins[NPR];                                   // 59392 B
        struct { float Ws[F_IN][F_HID]; float fs[4][F_IN]; } g;  // 31552 B
    } sm;
    int tid = threadIdx.x;
    if (blockIdx.x < NS * NR) {
        int slice = blockIdx.x >> 2;
        int r0 = (blockIdx.x & 3) * NPR;
        int ebase = slice * EPSL;
        // ---- dst histogram
        for (int k = tid; k < NPR; k += 256) sm.bins[k] = 0;
        __syncthreads();
        for (int k = tid; k < EPSL; k += 256) {
            int d = dst[ebase + k] - r0;
            if ((unsigned)d < NPR) atomicAdd(&sm.bins[d], 1u);
        }
        __syncthreads();
        for (int k = tid; k < NPR; k += 256)
            cnt2[(size_t)slice * N_NODES + r0 + k] = (unsigned short)sm.bins[k];
        __syncthreads();
        // ---- src histogram
        for (int k = tid; k < NPR; k += 256) sm.bins[k] = 0;
        __syncthreads();
        for (int k = tid; k < EPSL; k += 256) {
            int s = src[ebase + k] - r0;
            if ((unsigned)s < NPR) atomicAdd(&sm.bins[s], 1u);
        }
        __syncthreads();
        for (int k = tid; k < NPR; k += 256)
            cnt2s[(size_t)slice * N_NODES + r0 + k] = (unsigned short)sm.bins[k];
        __syncthreads();
    }
    // ---- gemm1: A1 = feat @ W1 (all 512 blocks; gemm-only blocks start immediately)
    int wave = tid >> 6;
    int lane = tid & 63;
    const int ngroups = N_NODES / 4;    // 14848
    for (int g = blockIdx.x; g < ngroups; g += gridDim.x) {
        int base = g * 4;
        __syncthreads();  // Ws/fs consumed (or bins dead on first iter)
        for (int i = tid; i < F_IN * F_HID; i += 256)  // reload W each iter: L1-hot, keeps union simple
            sm.g.Ws[i / F_HID][i % F_HID] = W1[i];
        for (int i = tid; i < 4 * F_IN; i += 256) {
            int r = i / F_IN, k = i - r * F_IN;
            sm.g.fs[r][k] = feat[(base + r) * F_IN + k];
        }
        __syncthreads();
        int node = base + wave;
        float a0 = 0.f, a1 = 0.f, a2 = 0.f, a3 = 0.f;
        #pragma unroll
        for (int k = 0; k < F_IN; k += 4) {  // 116 % 4 == 0
            a0 += sm.g.fs[wave][k + 0] * sm.g.Ws[k + 0][lane];
            a1 += sm.g.fs[wave][k + 1] * sm.g.Ws[k + 1][lane];
            a2 += sm.g.fs[wave][k + 2] * sm.g.Ws[k + 2][lane];
            a3 += sm.g.fs[wave][k + 3] * sm.g.Ws[k + 3][lane];
        }
        A1[node * F_HID + lane] = (a0 + a1) + (a2 + a3);
    }
}

// ---------------------------------------------------------------- kernel B: slice-prefix scan + norms
// Per node d: exclusive prefix of cnt2[i][d] over slices (in place), degrees -> norms.
__global__ __launch_bounds__(256) void scan_norm_kernel(unsigned short* __restrict__ cnt2,
                                                        const unsigned short* __restrict__ cnt2s,
                                                        float* __restrict__ onorm,
                                                        float* __restrict__ inorm,
                                                        int* __restrict__ ncnt) {
    int d = blockIdx.x * 256 + threadIdx.x;   // grid 232*256 == N_NODES exact
    int run = 0;
    for (int i = 0; i < NS; ++i) {
        size_t idx = (size_t)i * N_NODES + d;
        int c = cnt2[idx];
        cnt2[idx] = (unsigned short)run;      // exclusive slice-prefix
        run += c;
    }
    int o = 0;
    for (int i = 0; i < NS; ++i) o += cnt2s[(size_t)i * N_NODES + d];
    inorm[d] = rsqrtf(fmaxf((float)run, 1.0f));
    onorm[d] = rsqrtf(fmaxf((float)o, 1.0f));
    ncnt[d] = run < CCAP ? run : CCAP;
}

// ---------------------------------------------------------------- kernel C: deterministic placement
// LDS cursor = slice-prefix; pos = prefix + within-slice rank. No global atomics.
__global__ __launch_bounds__(256) void place_kernel(const int* __restrict__ src,
                                                    const int* __restrict__ dst,
                                                    const unsigned short* __restrict__ cnt2,
                                                    unsigned short* __restrict__ ebuf) {
    __shared__ unsigned cur[NPR];             // 59392 B
    int slice = blockIdx.x >> 2;
    int r0 = (blockIdx.x & 3) * NPR;
    int ebase = slice * EPSL;
    for (int k = threadIdx.x; k < NPR; k += 256)
        cur[k] = cnt2[(size_t)slice * N_NODES + r0 + k];
    __syncthreads();
    for (int k = threadIdx.x; k < EPSL; k += 256) {
        int d = dst[ebase + k];
        int dr = d - r0;
        if ((unsigned)dr < NPR) {
            unsigned pos = atomicAdd(&cur[dr], 1u);   // LDS atomic
            if (pos < CCAP) ebuf[(size_t)d * CCAP + pos] = (unsigned short)src[ebase + k];
        }
    }
}

// ---------------------------------------------------------------- fused gather1 + gemm2
// Per node v (one wave, lane = feature):
//   m = sum_{u->v} onorm[u]*A1[u];  h = relu(inorm[v]*m + b1)*onorm[v];  A2[v] = h @ W2
__global__ __launch_bounds__(256) void layer2_kernel(const int* __restrict__ ncnt,
                                                     const unsigned short* __restrict__ ebuf,
                                                     const float* __restrict__ A1,
                                                     const float* __restrict__ onorm,
                                                     const float* __restrict__ inorm,
                                                     const float* __restrict__ b1,
                                                     const float* __restrict__ W2,
                                                     float* __restrict__ A2) {
    int lane = threadIdx.x & 63;
    float w2[F_HID];                       // W2 column `lane` in VGPRs
    #pragma unroll
    for (int k = 0; k < F_HID; ++k) w2[k] = W2[k * F_HID + lane];
    float b1l = b1[lane];
    int wid = (blockIdx.x * 256 + threadIdx.x) >> 6;
    int nwaves = (gridDim.x * 256) >> 6;
    for (int v = wid; v < N_NODES; v += nwaves) {
        int n = ncnt[v];
        const unsigned short* eb = ebuf + (size_t)v * CCAP;
        float a0 = 0.f, a1 = 0.f, a2 = 0.f, a3 = 0.f;
        int j = 0;
        for (; j + 3 < n; j += 4) {
            unsigned long long p = *(const unsigned long long*)(eb + j);  // 4 indices
            int u0 = (int)(p & 0xFFFF), u1 = (int)((p >> 16) & 0xFFFF);
            int u2 = (int)((p >> 32) & 0xFFFF), u3 = (int)(p >> 48);
            a0 += onorm[u0] * A1[u0 * F_HID + lane];
            a1 += onorm[u1] * A1[u1 * F_HID + lane];
            a2 += onorm[u2] * A1[u2 * F_HID + lane];
            a3 += onorm[u3] * A1[u3 * F_HID + lane];
        }
        for (; j < n; ++j) { int u = eb[j]; a0 += onorm[u] * A1[u * F_HID + lane]; }
        float m = (a0 + a1) + (a2 + a3);
        float h = fmaxf(inorm[v] * m + b1l, 0.f) * onorm[v];
        float c0 = 0.f, c1 = 0.f, c2 = 0.f, c3 = 0.f;
        #pragma unroll
        for (int k = 0; k < F_HID; k += 4) {
            c0 += __shfl(h, k + 0) * w2[k + 0];
            c1 += __shfl(h, k + 1) * w2[k + 1];
            c2 += __shfl(h, k + 2) * w2[k + 2];
            c3 += __shfl(h, k + 3) * w2[k + 3];
        }
        A2[(size_t)v * F_HID + lane] = (c0 + c1) + (c2 + c3);
    }
}

// ---------------------------------------------------------------- fused gather2 + readout
__global__ __launch_bounds__(1024) void readout_kernel(const int* __restrict__ ncnt,
                                                       const unsigned short* __restrict__ ebuf,
                                                       const float* __restrict__ A2,
                                                       const float* __restrict__ inorm,
                                                       const float* __restrict__ b2,
                                                       const float* __restrict__ Wc,
                                                       const float* __restrict__ bc,
                                                       float* __restrict__ out) {
    int g = blockIdx.x;
    int wave = threadIdx.x >> 6, lane = threadIdx.x & 63;
    float b2l = b2[lane];
    float s0 = 0.f, s1 = 0.f;
    for (int nl = wave; nl < NPG; nl += 16) {
        int v = g * NPG + nl;
        int n = ncnt[v];
        const unsigned short* eb = ebuf + (size_t)v * CCAP;
        float a0 = 0.f, a1 = 0.f, a2 = 0.f, a3 = 0.f;
        int j = 0;
        for (; j + 3 < n; j += 4) {
            unsigned long long p = *(const unsigned long long*)(eb + j);
            int u0 = (int)(p & 0xFFFF), u1 = (int)((p >> 16) & 0xFFFF);
            int u2 = (int)((p >> 32) & 0xFFFF), u3 = (int)(p >> 48);
            a0 += A2[u0 * F_HID + lane];
            a1 += A2[u1 * F_HID + lane];
            a2 += A2[u2 * F_HID + lane];
            a3 += A2[u3 * F_HID + lane];
        }
        for (; j < n; ++j) a0 += A2[eb[j] * F_HID + lane];
        float m = (a0 + a1) + (a2 + a3);
        float h = fmaxf(inorm[v] * m + b2l, 0.f);
        float2 w = ((const float2*)Wc)[nl * F_HID + lane];
        s0 += h * w.x;
        s1 += h * w.y;
    }
    #pragma unroll
    for (int off = 32; off > 0; off >>= 1) {
        s0 += __shfl_down(s0, off);
        s1 += __shfl_down(s1, off);
    }
    __shared__ float ls[32];
    if (lane == 0) { ls[wave * 2] = s0; ls[wave * 2 + 1] = s1; }
    __syncthreads();
    if (threadIdx.x < 2) {
        float t = 0.f;
        #pragma unroll
        for (int w = 0; w < 16; ++w) t += ls[w * 2 + threadIdx.x];
        out[g * 2 + threadIdx.x] = t + bc[threadIdx.x];
    }
}

extern "C" void kernel_launch(void* const* d_in, const int* in_sizes, int n_in,
                              void* d_out, int out_size, void* d_ws, size_t ws_size,
                              hipStream_t stream) {
    const float* feat = (const float*)d_in[0];
    const int*   src  = (const int*)d_in[1];
    const int*   dst  = (const int*)d_in[2];
    // d_in[3] = batch_size (fixed 512)
    const float* W1 = (const float*)d_in[4];
    const float* b1 = (const float*)d_in[5];
    const float* W2 = (const float*)d_in[6];
    const float* b2 = (const float*)d_in[7];
    const float* Wc = (const float*)d_in[8];
    const float* bc = (const float*)d_in[9];
    float* out = (float*)d_out;

    // ws layout (≈38.7 MB, every kernel writes before reading — no memsets needed):
    // cnt2 u16[NS*N] | cnt2s u16[NS*N] | onorm f32[N] | inorm f32[N] | ncnt i32[N]
    // | ebuf u16[N*CCAP] | A1 f32[N*64] ;  A2 f32[N*64] ALIASES cnt2+cnt2s (dead after place)
    unsigned short* cnt2  = (unsigned short*)d_ws;
    unsigned short* cnt2s = cnt2 + (size_t)NS * N_NODES;
    float* onorm = (float*)(cnt2s + (size_t)NS * N_NODES);
    float* inorm = onorm + N_NODES;
    int* ncnt    = (int*)(inorm + N_NODES);
    unsigned short* ebuf = (unsigned short*)(ncnt + N_NODES);
    float* A1    = (float*)(ebuf + (size_t)N_NODES * CCAP);
    float* A2    = (float*)cnt2;   // 15.2 MB alias, first written in layer2

    hist_gemm1_kernel<<<512, 256, 0, stream>>>(src, dst, cnt2, cnt2s, feat, W1, A1);
    scan_norm_kernel<<<N_NODES / 256, 256, 0, stream>>>(cnt2, cnt2s, onorm, inorm, ncnt);
    place_kernel<<<NS * NR, 256, 0, stream>>>(src, dst, cnt2, ebuf);
    layer2_kernel<<<2048, 256, 0, stream>>>(ncnt, ebuf, A1, onorm, inorm, b1, W2, A2);
    readout_kernel<<<BATCH, 1024, 0, stream>>>(ncnt, ebuf, A2, inorm, b2, Wc, bc, out);
}

// Round 7
// 340.112 us; speedup vs baseline: 1.2141x; 1.2141x over previous
//
#include <hip/hip_runtime.h>

#define N_NODES 59392
#define N_EDGES 1187840
#define F_IN 116
#define F_HID 64
#define BATCH 512
#define NPG 116            // nodes per graph
#define CCAP 64            // bucket: 64 u16 = one 128B line per node; P(indeg>64)~1e-15, guarded
#define NSS 16             // src-histogram slices
#define NR 4               // node ranges
#define EPSS (N_EDGES / NSS)  // 74240 edges per src-slice (exact)
#define NPR (N_NODES / NR)    // 14848 nodes per range (exact)

__device__ __forceinline__ float bf2f(unsigned short h) {
    union { unsigned u; float f; } x; x.u = (unsigned)h << 16; return x.f;
}
__device__ __forceinline__ unsigned short f2bf(float f) {
    union { float f; unsigned u; } x; x.f = f;
    unsigned r = x.u + 0x7FFF + ((x.u >> 16) & 1);   // RNE
    return (unsigned short)(r >> 16);
}

// ---------------------------------------------------------------- fused build + src-hist + gemm1
// Role 1 (all 4640 blocks): one edge each thread — cursor atomic + bucket fill.
//   (1.19M global atomics, down from 2.4M: the out-deg half moved to LDS.)
// Role 2 (blocks 0..63): out-degree histogram of one src-slice into packed-u16 LDS
//   bins (29.7KB, unioned with Ws — no occupancy cost), written as clean u32 lines.
// Role 3 (all blocks): gemm1 A1 = feat @ W1, stored bf16 (onorm deferred by linearity).
__global__ __launch_bounds__(256) void build_gemm1_kernel(const int* __restrict__ src,
                                                          const int* __restrict__ dst,
                                                          unsigned* __restrict__ cursor,
                                                          unsigned short* __restrict__ ebuf,
                                                          unsigned short* __restrict__ cnts,
                                                          const float* __restrict__ feat,
                                                          const float* __restrict__ W1,
                                                          unsigned short* __restrict__ A1h) {
    __shared__ union {
        unsigned bins[NPR / 2];          // 29696 B: two u16 counts per u32
        float Ws[F_IN][F_HID];           // 29696 B
    } sm;
    __shared__ float fs[4][F_IN];
    int tid = threadIdx.x;
    // ---- edge phase (grid 4640*256 == N_EDGES exact)
    {
        int e = blockIdx.x * 256 + tid;
        int s = src[e], d = dst[e];
        unsigned pos = atomicAdd(&cursor[d], 1u);
        if (pos < CCAP) ebuf[(size_t)d * CCAP + pos] = (unsigned short)s;
    }
    // ---- src histogram (blocks 0..63): slice = b>>2, range = b&3
    if (blockIdx.x < NSS * NR) {
        int slice = blockIdx.x >> 2;
        int r0 = (blockIdx.x & 3) * NPR;
        int ebase = slice * EPSS;
        for (int k = tid; k < NPR / 2; k += 256) sm.bins[k] = 0;
        __syncthreads();
        for (int k = tid; k < EPSS; k += 256) {
            int s = src[ebase + k] - r0;
            if ((unsigned)s < NPR)
                atomicAdd(&sm.bins[s >> 1], 1u << ((s & 1) * 16));  // LDS atomic, packed
        }
        __syncthreads();
        unsigned* dstw = (unsigned*)cnts + (size_t)slice * (N_NODES / 2) + (r0 >> 1);
        for (int k = tid; k < NPR / 2; k += 256) dstw[k] = sm.bins[k];
        __syncthreads();   // bins dead before Ws overwrites
    }
    // ---- gemm1: A1 = feat @ W1 (bf16 out)
    for (int i = tid; i < F_IN * F_HID; i += 256)
        sm.Ws[i / F_HID][i % F_HID] = W1[i];
    int wave = tid >> 6;
    int lane = tid & 63;
    const int ngroups = N_NODES / 4;    // 14848
    for (int g = blockIdx.x; g < ngroups; g += gridDim.x) {
        int base = g * 4;
        __syncthreads();  // Ws ready (first iter) / fs consumed (later)
        for (int i = tid; i < 4 * F_IN; i += 256) {
            int r = i / F_IN, k = i - r * F_IN;
            fs[r][k] = feat[(base + r) * F_IN + k];
        }
        __syncthreads();
        int node = base + wave;
        float a0 = 0.f, a1 = 0.f, a2 = 0.f, a3 = 0.f;
        #pragma unroll
        for (int k = 0; k < F_IN; k += 4) {  // 116 % 4 == 0
            a0 += fs[wave][k + 0] * sm.Ws[k + 0][lane];
            a1 += fs[wave][k + 1] * sm.Ws[k + 1][lane];
            a2 += fs[wave][k + 2] * sm.Ws[k + 2][lane];
            a3 += fs[wave][k + 3] * sm.Ws[k + 3][lane];
        }
        A1h[node * F_HID + lane] = f2bf((a0 + a1) + (a2 + a3));
    }
}

// ---------------------------------------------------------------- norms
__global__ __launch_bounds__(256) void norm_kernel(const unsigned* __restrict__ cursor,
                                                   const unsigned short* __restrict__ cnts,
                                                   float* __restrict__ onorm,
                                                   float* __restrict__ inorm,
                                                   int* __restrict__ ncnt) {
    int i = blockIdx.x * 256 + threadIdx.x;   // grid 232*256 == N_NODES exact
    int o = 0;
    #pragma unroll
    for (int s = 0; s < NSS; ++s) o += cnts[(size_t)s * N_NODES + i];
    int c = cursor[i];
    onorm[i] = rsqrtf(fmaxf((float)o, 1.0f));
    inorm[i] = rsqrtf(fmaxf((float)c, 1.0f));
    ncnt[i] = c < CCAP ? c : CCAP;
}

// ---------------------------------------------------------------- fused gather1 + gemm2 (bf16 rows)
// Per node v (one wave, lane = feature):
//   m = sum_{u->v} onorm[u]*A1[u];  h = relu(inorm[v]*m + b1)*onorm[v];  A2[v] = h @ W2
__global__ __launch_bounds__(256) void layer2_kernel(const int* __restrict__ ncnt,
                                                     const unsigned short* __restrict__ ebuf,
                                                     const unsigned short* __restrict__ A1h,
                                                     const float* __restrict__ onorm,
                                                     const float* __restrict__ inorm,
                                                     const float* __restrict__ b1,
                                                     const float* __restrict__ W2,
                                                     unsigned short* __restrict__ A2h) {
    int lane = threadIdx.x & 63;
    float w2[F_HID];                       // W2 column `lane` in VGPRs
    #pragma unroll
    for (int k = 0; k < F_HID; ++k) w2[k] = W2[k * F_HID + lane];
    float b1l = b1[lane];
    int wid = (blockIdx.x * 256 + threadIdx.x) >> 6;
    int nwaves = (gridDim.x * 256) >> 6;
    for (int v = wid; v < N_NODES; v += nwaves) {
        int n = ncnt[v];
        const unsigned short* eb = ebuf + (size_t)v * CCAP;
        float a0 = 0.f, a1 = 0.f, a2 = 0.f, a3 = 0.f;
        int j = 0;
        for (; j + 3 < n; j += 4) {
            unsigned long long p = *(const unsigned long long*)(eb + j);  // 4 indices
            int u0 = (int)(p & 0xFFFF), u1 = (int)((p >> 16) & 0xFFFF);
            int u2 = (int)((p >> 32) & 0xFFFF), u3 = (int)(p >> 48);
            a0 += onorm[u0] * bf2f(A1h[u0 * F_HID + lane]);
            a1 += onorm[u1] * bf2f(A1h[u1 * F_HID + lane]);
            a2 += onorm[u2] * bf2f(A1h[u2 * F_HID + lane]);
            a3 += onorm[u3] * bf2f(A1h[u3 * F_HID + lane]);
        }
        for (; j < n; ++j) { int u = eb[j]; a0 += onorm[u] * bf2f(A1h[u * F_HID + lane]); }
        float m = (a0 + a1) + (a2 + a3);
        float h = fmaxf(inorm[v] * m + b1l, 0.f) * onorm[v];
        float c0 = 0.f, c1 = 0.f, c2 = 0.f, c3 = 0.f;
        #pragma unroll
        for (int k = 0; k < F_HID; k += 4) {
            c0 += __shfl(h, k + 0) * w2[k + 0];
            c1 += __shfl(h, k + 1) * w2[k + 1];
            c2 += __shfl(h, k + 2) * w2[k + 2];
            c3 += __shfl(h, k + 3) * w2[k + 3];
        }
        A2h[(size_t)v * F_HID + lane] = f2bf((c0 + c1) + (c2 + c3));
    }
}

// ---------------------------------------------------------------- fused gather2 + readout (bf16 rows)
__global__ __launch_bounds__(1024) void readout_kernel(const int* __restrict__ ncnt,
                                                       const unsigned short* __restrict__ ebuf,
                                                       const unsigned short* __restrict__ A2h,
                                                       const float* __restrict__ inorm,
                                                       const float* __restrict__ b2,
                                                       const float* __restrict__ Wc,
                                                       const float* __restrict__ bc,
                                                       float* __restrict__ out) {
    int g = blockIdx.x;
    int wave = threadIdx.x >> 6, lane = threadIdx.x & 63;
    float b2l = b2[lane];
    float s0 = 0.f, s1 = 0.f;
    for (int nl = wave; nl < NPG; nl += 16) {
        int v = g * NPG + nl;
        int n = ncnt[v];
        const unsigned short* eb = ebuf + (size_t)v * CCAP;
        float a0 = 0.f, a1 = 0.f, a2 = 0.f, a3 = 0.f;
        int j = 0;
        for (; j + 3 < n; j += 4) {
            unsigned long long p = *(const unsigned long long*)(eb + j);
            int u0 = (int)(p & 0xFFFF), u1 = (int)((p >> 16) & 0xFFFF);
            int u2 = (int)((p >> 32) & 0xFFFF), u3 = (int)(p >> 48);
            a0 += bf2f(A2h[u0 * F_HID + lane]);
            a1 += bf2f(A2h[u1 * F_HID + lane]);
            a2 += bf2f(A2h[u2 * F_HID + lane]);
            a3 += bf2f(A2h[u3 * F_HID + lane]);
        }
        for (; j < n; ++j) a0 += bf2f(A2h[eb[j] * F_HID + lane]);
        float m = (a0 + a1) + (a2 + a3);
        float h = fmaxf(inorm[v] * m + b2l, 0.f);
        float2 w = ((const float2*)Wc)[nl * F_HID + lane];
        s0 += h * w.x;
        s1 += h * w.y;
    }
    #pragma unroll
    for (int off = 32; off > 0; off >>= 1) {
        s0 += __shfl_down(s0, off);
        s1 += __shfl_down(s1, off);
    }
    __shared__ float ls[32];
    if (lane == 0) { ls[wave * 2] = s0; ls[wave * 2 + 1] = s1; }
    __syncthreads();
    if (threadIdx.x < 2) {
        float t = 0.f;
        #pragma unroll
        for (int w = 0; w < 16; ++w) t += ls[w * 2 + threadIdx.x];
        out[g * 2 + threadIdx.x] = t + bc[threadIdx.x];
    }
}

extern "C" void kernel_launch(void* const* d_in, const int* in_sizes, int n_in,
                              void* d_out, int out_size, void* d_ws, size_t ws_size,
                              hipStream_t stream) {
    const float* feat = (const float*)d_in[0];
    const int*   src  = (const int*)d_in[1];
    const int*   dst  = (const int*)d_in[2];
    // d_in[3] = batch_size (fixed 512)
    const float* W1 = (const float*)d_in[4];
    const float* b1 = (const float*)d_in[5];
    const float* W2 = (const float*)d_in[6];
    const float* b2 = (const float*)d_in[7];
    const float* Wc = (const float*)d_in[8];
    const float* bc = (const float*)d_in[9];
    float* out = (float*)d_out;

    // ws layout (≈25.6 MB, all 128B-aligned):
    // cursor u32[N] | cnts u16[NSS*N] | onorm f32[N] | inorm f32[N] | ncnt i32[N]
    // | ebuf u16[N*CCAP] | A1h bf16[N*64] | A2h bf16[N*64]
    unsigned* cursor = (unsigned*)d_ws;
    unsigned short* cnts = (unsigned short*)(cursor + N_NODES);
    float* onorm = (float*)(cnts + (size_t)NSS * N_NODES);
    float* inorm = onorm + N_NODES;
    int* ncnt    = (int*)(inorm + N_NODES);
    unsigned short* ebuf = (unsigned short*)(ncnt + N_NODES);
    unsigned short* A1h  = ebuf + (size_t)N_NODES * CCAP;
    unsigned short* A2h  = A1h + (size_t)N_NODES * F_HID;

    hipMemsetAsync(cursor, 0, N_NODES * sizeof(unsigned), stream);

    build_gemm1_kernel<<<N_EDGES / 256, 256, 0, stream>>>(src, dst, cursor, ebuf, cnts,
                                                          feat, W1, A1h);
    norm_kernel<<<N_NODES / 256, 256, 0, stream>>>(cursor, cnts, onorm, inorm, ncnt);
    layer2_kernel<<<2048, 256, 0, stream>>>(ncnt, ebuf, A1h, onorm, inorm, b1, W2, A2h);
    readout_kernel<<<BATCH, 1024, 0, stream>>>(ncnt, ebuf, A2h, inorm, b2, Wc, bc, out);
}